// Round 1
// baseline (438.977 us; speedup 1.0000x reference)
//
#include <hip/hip_runtime.h>
#include <cstdint>
#include <cstddef>

#define D 64

// ---------------- build compact slot maps ----------------
__global__ __launch_bounds__(256) void k_build_maps(const int* __restrict__ user_id,
                                                    const int* __restrict__ item_id,
                                                    int* __restrict__ map_u,
                                                    int* __restrict__ map_i, int B)
{
    int i = blockIdx.x * blockDim.x + threadIdx.x;
    if (i < B) {
        atomicCAS(&map_u[user_id[i]], -1, i);
        atomicCAS(&map_i[item_id[i]], -1, i);
    }
}

// ---------------- filtered edge aggregation ----------------
// wave processes 64 edges at a time; hits enumerated via ballot; 64 lanes
// cooperate on each 64-float row gather + atomic add into compact slots.
__global__ __launch_bounds__(256) void k_aggregate(const int* __restrict__ edge_user,
                                                   const int* __restrict__ edge_item,
                                                   const float* __restrict__ user_table,
                                                   const float* __restrict__ item_table,
                                                   const int* __restrict__ map_u,
                                                   const int* __restrict__ map_i,
                                                   float* __restrict__ aggIU,
                                                   float* __restrict__ aggUI,
                                                   int* __restrict__ degU,
                                                   int* __restrict__ degI, int E)
{
    int gtid = blockIdx.x * blockDim.x + threadIdx.x;
    int wid = gtid >> 6;
    int lane = threadIdx.x & 63;
    int nw = (gridDim.x * blockDim.x) >> 6;
    for (long long base = (long long)wid * 64; base < E; base += (long long)nw * 64) {
        int e = (int)base + lane;
        int u = 0, it = 0, su = -1, si = -1;
        if (e < E) {
            u  = edge_user[e];
            it = edge_item[e];
            su = map_u[u];
            si = map_i[it];
        }
        unsigned long long mU = __ballot(su >= 0);
        while (mU) {
            int src = __ffsll(mU) - 1;
            mU &= mU - 1;
            int s_su = __shfl(su, src);
            int s_it = __shfl(it, src);
            float v = item_table[(size_t)s_it * D + lane];
            atomicAdd(&aggIU[(size_t)s_su * D + lane], v);
            if (lane == 0) atomicAdd(&degU[s_su], 1);
        }
        unsigned long long mI = __ballot(si >= 0);
        while (mI) {
            int src = __ffsll(mI) - 1;
            mI &= mI - 1;
            int s_si = __shfl(si, src);
            int s_u  = __shfl(u, src);
            float v = user_table[(size_t)s_u * D + lane];
            atomicAdd(&aggUI[(size_t)s_si * D + lane], v);
            if (lane == 0) atomicAdd(&degI[s_si], 1);
        }
    }
}

// ---------------- per-row GCN transform + feature build ----------------
// one wave per output row; Wu/Wi staged in LDS per block.
__global__ __launch_bounds__(256) void k_build_x(const int* __restrict__ user_id,
                                                 const int* __restrict__ item_id,
                                                 const int* __restrict__ map_u,
                                                 const int* __restrict__ map_i,
                                                 const int* __restrict__ degU,
                                                 const int* __restrict__ degI,
                                                 const float* __restrict__ aggIU,
                                                 const float* __restrict__ aggUI,
                                                 const float* __restrict__ user_table,
                                                 const float* __restrict__ item_table,
                                                 const float* __restrict__ Wu,
                                                 const float* __restrict__ bu,
                                                 const float* __restrict__ Wi,
                                                 const float* __restrict__ bi,
                                                 float* __restrict__ x, int B)
{
    __shared__ float WuL[D * D];
    __shared__ float WiL[D * D];
    for (int t = threadIdx.x; t < D * D; t += blockDim.x) {
        WuL[t] = Wu[t];
        WiL[t] = Wi[t];
    }
    __syncthreads();

    int wid = (blockIdx.x * blockDim.x + threadIdx.x) >> 6;
    int lane = threadIdx.x & 63;
    if (wid >= B) return;

    int u  = user_id[wid];
    int it = item_id[wid];
    int su = map_u[u];
    int si = map_i[it];
    float du = (float)degU[su] + 1.0f;   // edges per user (+1)
    float di = (float)degI[si] + 1.0f;   // edges per item (+1)
    float gih = aggIU[(size_t)su * D + lane] / du;  // gcn_item_h[lane]
    float guh = aggUI[(size_t)si * D + lane] / di;  // gcn_user_h[lane]

    float accU = bu[lane];
    float accI = bi[lane];
    #pragma unroll 8
    for (int k = 0; k < D; ++k) {
        float gk = __shfl(guh, k);
        accU = fmaf(gk, WuL[k * D + lane], accU);
        float hk = __shfl(gih, k);
        accI = fmaf(hk, WiL[k * D + lane], accI);
    }
    float guo = fmaxf(accU, 0.0f);   // gcn_user_out
    float gio = fmaxf(accI, 0.0f);   // gcn_item_out
    float ue = user_table[(size_t)u * D + lane];
    float ie = item_table[(size_t)it * D + lane];

    size_t xb = (size_t)wid * 256;
    x[xb + lane]       = ue * ie;
    x[xb + 64 + lane]  = ue * gio;
    x[xb + 128 + lane] = guo * ie;
    x[xb + 192 + lane] = guo * gio;
}

// ---------------- layer 1: [B,256]@[256,128] + b1, tanh ----------------
__global__ __launch_bounds__(256) void k_gemm1(const float* __restrict__ x,
                                               const float* __restrict__ W1,
                                               const float* __restrict__ b1,
                                               float* __restrict__ x1, int B)
{
    __shared__ float xs[32][65];    // [k][row], padded
    __shared__ float ws[32][128];
    int tid = threadIdx.x;
    int tx = tid & 31;      // col group (cols tx + 32*c)
    int ty = tid >> 5;      // row group (rows ty*8 + r)
    int row0 = blockIdx.x * 64;
    float acc[8][4] = {};

    for (int k0 = 0; k0 < 256; k0 += 32) {
        // x tile 64 rows x 32 k
        {
            int r = tid >> 2;
            int kk = (tid & 3) * 8;
            const float4* src = (const float4*)&x[(size_t)(row0 + r) * 256 + k0 + kk];
            float4 v0 = src[0], v1 = src[1];
            xs[kk + 0][r] = v0.x; xs[kk + 1][r] = v0.y; xs[kk + 2][r] = v0.z; xs[kk + 3][r] = v0.w;
            xs[kk + 4][r] = v1.x; xs[kk + 5][r] = v1.y; xs[kk + 6][r] = v1.z; xs[kk + 7][r] = v1.w;
        }
        // W1 tile 32 k x 128 (contiguous 4096 floats)
        {
            const float4* src = (const float4*)(W1 + (size_t)k0 * 128);
            float4* dst = (float4*)&ws[0][0];
            #pragma unroll
            for (int q = 0; q < 4; ++q) dst[tid + q * 256] = src[tid + q * 256];
        }
        __syncthreads();
        #pragma unroll
        for (int k = 0; k < 32; ++k) {
            float a[8], b[4];
            #pragma unroll
            for (int r = 0; r < 8; ++r) a[r] = xs[k][ty * 8 + r];
            #pragma unroll
            for (int c = 0; c < 4; ++c) b[c] = ws[k][tx + 32 * c];
            #pragma unroll
            for (int r = 0; r < 8; ++r)
                #pragma unroll
                for (int c = 0; c < 4; ++c)
                    acc[r][c] = fmaf(a[r], b[c], acc[r][c]);
        }
        __syncthreads();
    }
    #pragma unroll
    for (int r = 0; r < 8; ++r) {
        int row = row0 + ty * 8 + r;
        #pragma unroll
        for (int c = 0; c < 4; ++c) {
            int col = tx + 32 * c;
            x1[(size_t)row * 128 + col] = tanhf(acc[r][c] + b1[col]);
        }
    }
}

// ---------------- layer 2: [B,128]@[128,64] + b2, tanh ----------------
__global__ __launch_bounds__(256) void k_gemm2(const float* __restrict__ x1,
                                               const float* __restrict__ W2,
                                               const float* __restrict__ b2,
                                               float* __restrict__ x2, int B)
{
    __shared__ float xs[32][65];    // [k][row]
    __shared__ float ws[32][64];
    int tid = threadIdx.x;
    int tx = tid & 15;      // cols tx + 16*c
    int ty = tid >> 4;      // rows ty*4 + r
    int row0 = blockIdx.x * 64;
    float acc[4][4] = {};

    for (int k0 = 0; k0 < 128; k0 += 32) {
        {
            int r = tid >> 2;
            int kk = (tid & 3) * 8;
            const float4* src = (const float4*)&x1[(size_t)(row0 + r) * 128 + k0 + kk];
            float4 v0 = src[0], v1 = src[1];
            xs[kk + 0][r] = v0.x; xs[kk + 1][r] = v0.y; xs[kk + 2][r] = v0.z; xs[kk + 3][r] = v0.w;
            xs[kk + 4][r] = v1.x; xs[kk + 5][r] = v1.y; xs[kk + 6][r] = v1.z; xs[kk + 7][r] = v1.w;
        }
        {
            const float4* src = (const float4*)(W2 + (size_t)k0 * 64);
            float4* dst = (float4*)&ws[0][0];
            #pragma unroll
            for (int q = 0; q < 2; ++q) dst[tid + q * 256] = src[tid + q * 256];
        }
        __syncthreads();
        #pragma unroll
        for (int k = 0; k < 32; ++k) {
            float a[4], b[4];
            #pragma unroll
            for (int r = 0; r < 4; ++r) a[r] = xs[k][ty * 4 + r];
            #pragma unroll
            for (int c = 0; c < 4; ++c) b[c] = ws[k][tx + 16 * c];
            #pragma unroll
            for (int r = 0; r < 4; ++r)
                #pragma unroll
                for (int c = 0; c < 4; ++c)
                    acc[r][c] = fmaf(a[r], b[c], acc[r][c]);
        }
        __syncthreads();
    }
    #pragma unroll
    for (int r = 0; r < 4; ++r) {
        int row = row0 + ty * 4 + r;
        #pragma unroll
        for (int c = 0; c < 4; ++c) {
            int col = tx + 16 * c;
            x2[(size_t)row * 64 + col] = tanhf(acc[r][c] + b2[col]);
        }
    }
}

// ---------------- final: dot with W3 + biases ----------------
__global__ __launch_bounds__(256) void k_final(const float* __restrict__ x2,
                                               const float* __restrict__ W3,
                                               const float* __restrict__ b3,
                                               const float* __restrict__ user_bias,
                                               const float* __restrict__ item_bias,
                                               const int* __restrict__ user_id,
                                               const int* __restrict__ item_id,
                                               float* __restrict__ out, int B)
{
    int wid = (blockIdx.x * blockDim.x + threadIdx.x) >> 6;
    int lane = threadIdx.x & 63;
    if (wid >= B) return;
    float v = x2[(size_t)wid * 64 + lane] * W3[lane];
    #pragma unroll
    for (int off = 32; off; off >>= 1) v += __shfl_xor(v, off);
    if (lane == 0)
        out[wid] = v + b3[0] + user_bias[user_id[wid]] + item_bias[item_id[wid]];
}

extern "C" void kernel_launch(void* const* d_in, const int* in_sizes, int n_in,
                              void* d_out, int out_size, void* d_ws, size_t ws_size,
                              hipStream_t stream)
{
    const float* user_table = (const float*)d_in[0];
    const float* item_table = (const float*)d_in[1];
    const float* Wu = (const float*)d_in[2];
    const float* bu = (const float*)d_in[3];
    const float* Wi = (const float*)d_in[4];
    const float* bi = (const float*)d_in[5];
    const float* W1 = (const float*)d_in[6];
    const float* b1 = (const float*)d_in[7];
    const float* W2 = (const float*)d_in[8];
    const float* b2 = (const float*)d_in[9];
    const float* W3 = (const float*)d_in[10];
    const float* b3 = (const float*)d_in[11];
    const float* user_bias = (const float*)d_in[12];
    const float* item_bias = (const float*)d_in[13];
    const int* user_id = (const int*)d_in[14];
    const int* item_id = (const int*)d_in[15];
    const int* edge_user = (const int*)d_in[16];
    const int* edge_item = (const int*)d_in[17];

    const int N_USER = in_sizes[0] / D;
    const int N_ITEM = in_sizes[1] / D;
    const int B = in_sizes[14];
    const int E = in_sizes[16];

    // ---- workspace layout (bytes) ----
    char* ws = (char*)d_ws;
    const size_t aggIU_off = 0;
    const size_t aggUI_off = aggIU_off + (size_t)B * D * 4;        // 4 MB
    const size_t degU_off  = aggUI_off + (size_t)B * D * 4;        // 8 MB
    const size_t degI_off  = degU_off + (size_t)B * 4;
    const size_t mapu_off  = degI_off + (size_t)B * 4;
    const size_t mapi_off  = mapu_off + (size_t)N_USER * 4;
    size_t x_off = mapi_off + (size_t)N_ITEM * 4;
    x_off = (x_off + 255) & ~(size_t)255;
    const size_t x1_off = x_off + (size_t)B * 256 * 4;
    const size_t x2_off = x1_off + (size_t)B * 128 * 4;

    float* aggIU = (float*)(ws + aggIU_off);
    float* aggUI = (float*)(ws + aggUI_off);
    int*   degU  = (int*)(ws + degU_off);
    int*   degI  = (int*)(ws + degI_off);
    int*   map_u = (int*)(ws + mapu_off);
    int*   map_i = (int*)(ws + mapi_off);
    float* x  = (float*)(ws + x_off);
    float* x1 = (float*)(ws + x1_off);
    float* x2 = (float*)(ws + x2_off);

    // zero agg buffers + deg counters in one shot (contiguous), maps to -1
    hipMemsetAsync(ws + aggIU_off, 0, (size_t)B * D * 8 + (size_t)B * 8, stream);
    hipMemsetAsync(ws + mapu_off, 0xFF, (size_t)(N_USER + N_ITEM) * 4, stream);

    k_build_maps<<<(B + 255) / 256, 256, 0, stream>>>(user_id, item_id, map_u, map_i, B);

    k_aggregate<<<2048, 256, 0, stream>>>(edge_user, edge_item, user_table, item_table,
                                          map_u, map_i, aggIU, aggUI, degU, degI, E);

    k_build_x<<<B / 4, 256, 0, stream>>>(user_id, item_id, map_u, map_i, degU, degI,
                                         aggIU, aggUI, user_table, item_table,
                                         Wu, bu, Wi, bi, x, B);

    k_gemm1<<<B / 64, 256, 0, stream>>>(x, W1, b1, x1, B);
    k_gemm2<<<B / 64, 256, 0, stream>>>(x1, W2, b2, x2, B);

    k_final<<<B / 4, 256, 0, stream>>>(x2, W3, b3, user_bias, item_bias,
                                       user_id, item_id, (float*)d_out, B);
}